// Round 12
// baseline (34.353 us; speedup 1.0000x reference)
//
#include <hip/hip_runtime.h>

// Separable cubic-B-spline coefficient->value filter:
// out = F_D(F_H(F_W(coeff))), 3-tap [1/6, 4/6, 1/6], zero padding.
// Shape: (B*C=4, D=160, H=192, W=160), fp32.
//
// R12 = R11 pipeline (3-slot LDS ring, global_load_lds, counted vmcnt, raw
// s_barrier, direct f32x2 stores, XCD swizzle), single lever changed:
//   Zt 10 -> 5: grid 768 -> 1536 blocks. LDS (39.4 KB) keeps 4 blocks/CU
//   resident with a 6-deep queue -> deeper independent block pipelines to
//   fill the ~65% idle cycles R11's budget exposed. Cost: staged-slice
//   redundancy 1.2 -> 1.4 (L3-absorbed).
// A/B read: <=28 us => latency-bound confirmed; >=30 us => L2-fabric
// ceiling, R11/R12 is the roofline.
//
// vmcnt ledger (per wave; stage = 5 gload_lds, stores = 5/iter, in-order;
// stage(i+3) at top of iter i, stores at end of iter i), Zt=5:
//   prologue: [s-1,s0,s1]=15; want s-1 -> VMCNT(10); want s0 -> VMCNT(5)
//   iter 0: [s1,s2] want s1 -> VMCNT(5)
//   iter 1: [s2,s3,st0] want s2 -> VMCNT(10)
//   iter 2: [s3,st0,s4,st1] want s3 -> VMCNT(15)
//   iter 3: want s4 -> [st1,s5,st2] -> VMCNT(15)
//   iter 4: want s5 -> [st2,st3] -> VMCNT(10)
// (identical constants to R11's Zt=10 ledger; schedule code unchanged)
// WAR: slot overwritten by stage(i+3) was last read at iter i-1, sealed by
// iter i's top barrier.

typedef float f32x2 __attribute__((ext_vector_type(2)));

static constexpr int Dd = 160, Hh = 192, Ww = 160, BC = 4;
static constexpr int Zt = 5, Yt = 16;
static constexpr int NZB = Dd / Zt;   // 32
static constexpr int NYB = Hh / Yt;   // 12
static constexpr float KW1 = 1.0f / 6.0f;
static constexpr float KW0 = 2.0f / 3.0f;

// Input patch row: 164 floats = 656 B = 41*16 B (one gload16 per row;
// lane 0 fills the 4-float front pad with w=0..3, lanes 1..40 fill w=0..159).
static constexpr int ROWF   = 164;
static constexpr int PROWS  = 20;            // 18 used + 2 dummy (uniform 5/wave)
static constexpr int PATCHF = PROWS * ROWF;  // 3280 floats; 3 slots = 39,360 B

#define VMCNT(n) asm volatile("s_waitcnt vmcnt(" #n ")" ::: "memory")
#define BAR()    __builtin_amdgcn_s_barrier()

__device__ __forceinline__ void gload16(const float* g, float* l) {
    __builtin_amdgcn_global_load_lds(
        (const __attribute__((address_space(1))) float*)g,
        (__attribute__((address_space(3))) float*)l, 16, 0, 0);
}

struct YF { float v[12]; };   // y-filtered row at w = 10wc-1 .. 10wc+10

__global__ __launch_bounds__(256, 4) void CoeffToValue_kernel(
    const float* __restrict__ in, float* __restrict__ out)
{
    __shared__ __align__(16) float lds[3 * PATCHF];

    const int tid  = threadIdx.x;
    const int lane = tid & 63;
    const int wave = tid >> 6;
    const int wc   = tid & 15;     // w-chunk: outputs [10wc, 10wc+10)
    const int yo   = tid >> 4;     // y-output within tile: 0..15

    // T1: bijective XCD-chunked swizzle (1536 blocks, 8 XCDs, 192/XCD).
    const int bid = ((blockIdx.x & 7) * 192) + (blockIdx.x >> 3);
    const int zc  = bid % NZB;
    const int yb  = (bid / NZB) % NYB;
    const int bc  = bid / (NZB * NYB);
    const int z0  = zc * Zt;
    const int y0  = yb * Yt;

    // y-tap weights; zero boundary folded into weights (clamped rows finite).
    float cyw[3];
    {
        const float wy[3] = {KW1, KW0, KW1};
#pragma unroll
        for (int dy = 0; dy < 3; ++dy) {
            const int g = y0 + yo + dy - 1;
            cyw[dy] = (g >= 0 && g < Hh) ? wy[dy] : 0.0f;
        }
    }

    const size_t plane = (size_t)Hh * Ww;
    const float* inb = in + (size_t)bc * Dd * plane;

    // per-lane global w-offset for row staging (lane 0 feeds the front pad)
    const int woff = (lane == 0) ? 0 : 4 * (lane - 1);

    // Stage slice z0+k into ring slot (k+3)%3: 5 instr/wave, 1 row each.
    auto stage = [&](int k) {
        int zs = z0 + k;
        zs = zs < 0 ? 0 : (zs >= Dd ? Dd - 1 : zs);
        const float* sp = inb + (size_t)zs * plane;
        float* slot = lds + ((k + 3) % 3) * PATCHF;
        if (lane < 41) {
#pragma unroll
            for (int r = 0; r < 5; ++r) {
                const int p  = wave + 4 * r;          // LDS row 0..19
                const int ps = p > 17 ? 17 : p;       // dummies re-read row 17
                int ys = y0 - 1 + ps;
                ys = ys < 0 ? 0 : (ys >= Hh ? Hh - 1 : ys);
                gload16(sp + (size_t)ys * Ww + woff, slot + p * ROWF);
            }
        }
    };

    // y-filter slice z0+k at (yo, wc) from LDS into registers.
    auto yfilter = [&](int k) -> YF {
        const float* base = lds + ((k + 3) % 3) * PATCHF + 10 * wc + 2;
        YF o;
#pragma unroll
        for (int q = 0; q < 12; ++q) o.v[q] = 0.0f;
#pragma unroll
        for (int dy = 0; dy < 3; ++dy) {
            const float* rp = base + (yo + dy) * ROWF;
            float v[14];
#pragma unroll
            for (int r = 0; r < 7; ++r) {
                f32x2 p2 = *reinterpret_cast<const f32x2*>(rp + 2 * r);
                v[2 * r] = p2.x; v[2 * r + 1] = p2.y;
            }
            const float c = cyw[dy];
#pragma unroll
            for (int q = 0; q < 12; ++q) o.v[q] = fmaf(c, v[q + 1], o.v[q]);
        }
        return o;
    };

    // --- prologue: slices -1,0,1 staged; yf ring primed; slice 2 issued ---
    stage(-1); stage(0); stage(1);          // 15 outstanding
    VMCNT(10); BAR();                       // stage(-1) landed (all waves)
    YF a = yfilter(-1);
    VMCNT(5); BAR();                        // stage(0) landed; slot reads done
    stage(2);                               // reuses slice -1's slot
    YF b = yfilter(0);

#pragma unroll
    for (int i = 0; i < Zt; ++i) {
        if (i == 0)           { VMCNT(5);  }
        else if (i == 1)      { VMCNT(10); }
        else if (i == Zt - 1) { VMCNT(10); }
        else                  { VMCNT(15); }
        BAR();                              // stage(i+1) resident block-wide
        if (i <= Zt - 3) stage(i + 3);      // into slice i's slot (reads sealed)
        YF n = yfilter(i + 1);

        const int z = z0 + i;
        const float czm = (z > 0)      ? KW1 : 0.0f;
        const float czp = (z < Dd - 1) ? KW1 : 0.0f;

        float t[12];
#pragma unroll
        for (int q = 0; q < 12; ++q)
            t[q] = fmaf(czm, a.v[q], fmaf(KW0, b.v[q], czp * n.v[q]));
        // w-boundary: select (not multiply) so pad garbage cannot leak
        t[0]  = (wc > 0)  ? t[0]  : 0.0f;
        t[11] = (wc < 15) ? t[11] : 0.0f;

        float* orow = out + ((size_t)(bc * Dd + z) * Hh + (y0 + yo)) * Ww + 10 * wc;
#pragma unroll
        for (int s = 0; s < 5; ++s) {
            f32x2 o2;
            o2.x = fmaf(KW0, t[2 * s + 1], KW1 * (t[2 * s]     + t[2 * s + 2]));
            o2.y = fmaf(KW0, t[2 * s + 2], KW1 * (t[2 * s + 1] + t[2 * s + 3]));
            *reinterpret_cast<f32x2*>(orow + 2 * s) = o2;
        }

        a = b; b = n;                       // reg-resident yf ring rotate
    }
}

extern "C" void kernel_launch(void* const* d_in, const int* in_sizes, int n_in,
                              void* d_out, int out_size, void* d_ws, size_t ws_size,
                              hipStream_t stream) {
    const float* in = (const float*)d_in[0];
    float* out = (float*)d_out;

    const int blocks = BC * NYB * NZB;   // 4*12*32 = 1536 (4 resident/CU, 6 queued)
    CoeffToValue_kernel<<<blocks, 256, 0, stream>>>(in, out);
}

// Round 13
// 30.904 us; speedup vs baseline: 1.1116x; 1.1116x over previous
//
#include <hip/hip_runtime.h>

// Separable cubic-B-spline coefficient->value filter:
// out = F_D(F_H(F_W(coeff))), 3-tap [1/6, 4/6, 1/6], zero padding.
// Shape: (B*C=4, D=160, H=192, W=160), fp32.
//
// R13 = R11 (Zt=10, 768 blocks = exactly 3/CU, 3-slot LDS ring,
// global_load_lds, counted vmcnt, raw s_barrier, XCD swizzle) minus the
// 2 dummy staging rows: PROWS 20 -> 18 (Ry 1.25 -> 1.125).
// Wave-split staging: waves 0-1 stage 5 rows, waves 2-3 stage 4 rows
// (rows 0..17 exactly once). vmcnt is per-wave -> wave-uniform branches
// select the ledger constants.
//
// vmcnt ledger (stores = 5/iter all waves; stage = Sw = 5 (waves 0-1) or
// 4 (waves 2-3); in-order retire; stage(i+3) at top of iter i, stores at
// end of iter i):
//   prologue: [s-1,s0,s1] -> want s-1: suffix 2Sw -> 10/8; want s0 -> 5/4
//   iter 0: [s1,s2] -> want s1: suffix Sw -> 5/4
//   iter 1: [s2,s3,st0] -> want s2: suffix Sw+5 -> 10/9
//   iter 2..Zt-2: [s(i+1),st(i-2),s(i+2),st(i-1)] -> 5+Sw+5 -> 15/14
//   iter Zt-1: [sZt,st,st] -> suffix 10 -> 10/10
// WAR: slot overwritten by stage(i+3) was last read at iter i-1, sealed by
// iter i's top barrier.
//
// Fabric model (R8-R12): time = L2-side bytes / ~6.8 TB/s. R13 L2-side =
// 768*12*18*656 B + 78.6 MB = 187.5 MB -> ~29.3 us predicted.

typedef float f32x2 __attribute__((ext_vector_type(2)));

static constexpr int Dd = 160, Hh = 192, Ww = 160, BC = 4;
static constexpr int Zt = 10, Yt = 16;
static constexpr int NZB = Dd / Zt;   // 16
static constexpr int NYB = Hh / Yt;   // 12
static constexpr float KW1 = 1.0f / 6.0f;
static constexpr float KW0 = 2.0f / 3.0f;

// Input patch row: 164 floats = 656 B = 41*16 B (one gload16 per row;
// lane 0 fills the 4-float front pad with w=0..3, lanes 1..40 fill w=0..159).
static constexpr int ROWF   = 164;
static constexpr int PROWS  = 18;            // rows y0-1 .. y0+16, no dummies
static constexpr int PATCHF = PROWS * ROWF;  // 2952 floats; 3 slots = 35,424 B

#define VMCNT(n) asm volatile("s_waitcnt vmcnt(" #n ")" ::: "memory")
#define BAR()    __builtin_amdgcn_s_barrier()

__device__ __forceinline__ void gload16(const float* g, float* l) {
    __builtin_amdgcn_global_load_lds(
        (const __attribute__((address_space(1))) float*)g,
        (__attribute__((address_space(3))) float*)l, 16, 0, 0);
}

struct YF { float v[12]; };   // y-filtered row at w = 10wc-1 .. 10wc+10

__global__ __launch_bounds__(256, 4) void CoeffToValue_kernel(
    const float* __restrict__ in, float* __restrict__ out)
{
    __shared__ __align__(16) float lds[3 * PATCHF];

    const int tid  = threadIdx.x;
    const int lane = tid & 63;
    const int wave = tid >> 6;
    const bool w01 = (wave < 2);   // 5-row staging waves (else 4-row)
    const int wc   = tid & 15;     // w-chunk: outputs [10wc, 10wc+10)
    const int yo   = tid >> 4;     // y-output within tile: 0..15

    // T1: bijective XCD-chunked swizzle (768 blocks, 8 XCDs, 96/XCD).
    const int bid = ((blockIdx.x & 7) * 96) + (blockIdx.x >> 3);
    const int zc  = bid % NZB;
    const int yb  = (bid / NZB) % NYB;
    const int bc  = bid / (NZB * NYB);
    const int z0  = zc * Zt;
    const int y0  = yb * Yt;

    // y-tap weights; zero boundary folded into weights (clamped rows finite).
    float cyw[3];
    {
        const float wy[3] = {KW1, KW0, KW1};
#pragma unroll
        for (int dy = 0; dy < 3; ++dy) {
            const int g = y0 + yo + dy - 1;
            cyw[dy] = (g >= 0 && g < Hh) ? wy[dy] : 0.0f;
        }
    }

    const size_t plane = (size_t)Hh * Ww;
    const float* inb = in + (size_t)bc * Dd * plane;

    // per-lane global w-offset for row staging (lane 0 feeds the front pad)
    const int woff = (lane == 0) ? 0 : 4 * (lane - 1);

    // Stage slice z0+k into ring slot (k+3)%3.
    // Waves 0-1: rows {w, w+4, w+8, w+12, w+16} (5 instr).
    // Waves 2-3: rows {w, w+4, w+8, w+12}        (4 instr). Rows 0..17 once.
    auto stage = [&](int k) {
        int zs = z0 + k;
        zs = zs < 0 ? 0 : (zs >= Dd ? Dd - 1 : zs);
        const float* sp = inb + (size_t)zs * plane;
        float* slot = lds + ((k + 3) % 3) * PATCHF;
        if (lane < 41) {
#pragma unroll
            for (int r = 0; r < 4; ++r) {
                const int p = wave + 4 * r;          // rows 0..15
                int ys = y0 - 1 + p;
                ys = ys < 0 ? 0 : (ys >= Hh ? Hh - 1 : ys);
                gload16(sp + (size_t)ys * Ww + woff, slot + p * ROWF);
            }
            if (w01) {
                const int p = wave + 16;             // rows 16, 17
                int ys = y0 - 1 + p;                 // (y0+15/16; clamp for top)
                ys = ys >= Hh ? Hh - 1 : ys;
                gload16(sp + (size_t)ys * Ww + woff, slot + p * ROWF);
            }
        }
    };

    // y-filter slice z0+k at (yo, wc) from LDS into registers.
    auto yfilter = [&](int k) -> YF {
        const float* base = lds + ((k + 3) % 3) * PATCHF + 10 * wc + 2;
        YF o;
#pragma unroll
        for (int q = 0; q < 12; ++q) o.v[q] = 0.0f;
#pragma unroll
        for (int dy = 0; dy < 3; ++dy) {
            const float* rp = base + (yo + dy) * ROWF;
            float v[14];
#pragma unroll
            for (int r = 0; r < 7; ++r) {
                f32x2 p2 = *reinterpret_cast<const f32x2*>(rp + 2 * r);
                v[2 * r] = p2.x; v[2 * r + 1] = p2.y;
            }
            const float c = cyw[dy];
#pragma unroll
            for (int q = 0; q < 12; ++q) o.v[q] = fmaf(c, v[q + 1], o.v[q]);
        }
        return o;
    };

    // --- prologue: slices -1,0,1 staged; yf ring primed; slice 2 issued ---
    stage(-1); stage(0); stage(1);
    if (w01) { VMCNT(10); } else { VMCNT(8); }
    BAR();                                  // stage(-1) landed (all waves)
    YF a = yfilter(-1);
    if (w01) { VMCNT(5); } else { VMCNT(4); }
    BAR();                                  // stage(0) landed; slot reads done
    stage(2);                               // reuses slice -1's slot
    YF b = yfilter(0);

#pragma unroll
    for (int i = 0; i < Zt; ++i) {
        if (i == 0)           { if (w01) { VMCNT(5);  } else { VMCNT(4);  } }
        else if (i == 1)      { if (w01) { VMCNT(10); } else { VMCNT(9);  } }
        else if (i == Zt - 1) { VMCNT(10); }
        else                  { if (w01) { VMCNT(15); } else { VMCNT(14); } }
        BAR();                              // stage(i+1) resident block-wide
        if (i <= Zt - 3) stage(i + 3);      // into slice i's slot (reads sealed)
        YF n = yfilter(i + 1);

        const int z = z0 + i;
        const float czm = (z > 0)      ? KW1 : 0.0f;
        const float czp = (z < Dd - 1) ? KW1 : 0.0f;

        float t[12];
#pragma unroll
        for (int q = 0; q < 12; ++q)
            t[q] = fmaf(czm, a.v[q], fmaf(KW0, b.v[q], czp * n.v[q]));
        // w-boundary: select (not multiply) so pad garbage cannot leak
        t[0]  = (wc > 0)  ? t[0]  : 0.0f;
        t[11] = (wc < 15) ? t[11] : 0.0f;

        float* orow = out + ((size_t)(bc * Dd + z) * Hh + (y0 + yo)) * Ww + 10 * wc;
#pragma unroll
        for (int s = 0; s < 5; ++s) {
            f32x2 o2;
            o2.x = fmaf(KW0, t[2 * s + 1], KW1 * (t[2 * s]     + t[2 * s + 2]));
            o2.y = fmaf(KW0, t[2 * s + 2], KW1 * (t[2 * s + 1] + t[2 * s + 3]));
            *reinterpret_cast<f32x2*>(orow + 2 * s) = o2;
        }

        a = b; b = n;                       // reg-resident yf ring rotate
    }
}

extern "C" void kernel_launch(void* const* d_in, const int* in_sizes, int n_in,
                              void* d_out, int out_size, void* d_ws, size_t ws_size,
                              hipStream_t stream) {
    const float* in = (const float*)d_in[0];
    float* out = (float*)d_out;

    const int blocks = BC * NYB * NZB;   // 4*12*16 = 768 = exactly 3/CU
    CoeffToValue_kernel<<<blocks, 256, 0, stream>>>(in, out);
}